// Round 7
// baseline (2369.011 us; speedup 1.0000x reference)
//
#include <hip/hip_runtime.h>
#include <hip/hip_bf16.h>
#include <cstddef>

typedef __hip_bfloat16 bf16;
typedef short short8 __attribute__((ext_vector_type(8)));
typedef float float4v __attribute__((ext_vector_type(4)));
#define DEV static __device__ __forceinline__

constexpr int NB = 16;     // batch
constexpr int SEQL = 20;
constexpr int CD = 256;    // VD
constexpr int PP = 1024;   // 32*32
constexpr int HND = 512;
constexpr int EMBD = 300;
constexpr int CIN = 776;   // 256 + 8 + 512

// ---- workspace layout (float element offsets); bf16 buffers are [n][p][c] ----
constexpr size_t SZB = (size_t)NB * PP * CD / 2;             // floats per bf16 NPC buffer
constexpr size_t OF_FEATB = 0;                               // running feature (bf16)
constexpr size_t OF_TB   = 1*SZB;                            // t (bf16)
constexpr size_t OF_KHB  = 2*SZB;                            // kh (bf16)
constexpr size_t OF_VVB  = 3*SZB;                            // vv (bf16)
constexpr size_t OF_AOB  = 4*SZB;                            // attn out (bf16)
constexpr size_t OF_QH   = 7*SZB;                            // qh [s][n][c] fp32
constexpr size_t OF_HNW  = OF_QH  + (size_t)SEQL*NB*CD;      // hnW [r][n][o] fp32
constexpr size_t OF_SCV  = OF_HNW + (size_t)9*NB*CD;         // sconv [p][o] fp32
constexpr size_t OF_WRG  = OF_SCV + (size_t)PP*CD;           // W_region [r][o][c] fp32
constexpr size_t OF_AW   = OF_WRG + (size_t)9*CD*HND;        // conv W A-frags (589,824 bf16)
constexpr size_t OF_PK   = OF_AW  + (size_t)294912;          // linear W B-frags: 5 x 65,536 bf16
constexpr size_t OF_FLAG = OF_PK  + (size_t)163840;          // dtype flag

DEV float bf2f(bf16 v) { return __bfloat162float(v); }
DEV bf16 f2bf(float v) { return __float2bfloat16(v); }

DEV float LD(const void* p, size_t i, int bf) {
  return bf ? __bfloat162float(((const bf16*)p)[i]) : ((const float*)p)[i];
}
DEV int get_bf(const float* ws) { return ((const int*)ws)[OF_FLAG]; }

__global__ void k_detect(const void* g, float* ws) {
  if (threadIdx.x == 0 && blockIdx.x == 0) {
    unsigned w = *(const unsigned*)g;
    ((int*)ws)[OF_FLAG] = ((w & 0xFFFFu) != 0u) ? 1 : 0;
  }
}

// LN reduction, 256 threads: tile[o][x] stride 33; red[512+x]=mean, red[544+x]=rstd
DEV void ln_reduce(const float* tile, float* red, int tid) {
  const int x = tid & 31, seg = tid >> 5;
  float s = 0.f, sq = 0.f;
  for (int i = 0; i < 32; ++i) {
    float v = tile[(seg*32 + i)*33 + x];
    s += v; sq += v*v;
  }
  red[seg*32 + x] = s;
  red[256 + seg*32 + x] = sq;
  __syncthreads();
  if (tid < 32) {
    float ts = 0.f, tq = 0.f;
    for (int g = 0; g < 8; ++g) { ts += red[g*32 + tid]; tq += red[256 + g*32 + tid]; }
    float m = ts * (1.f/CD);
    float var = tq * (1.f/CD) - m*m;
    red[512 + tid] = m;
    red[544 + tid] = 1.f / sqrtf(var + 1e-5f);
  }
  __syncthreads();
}

// stage 32 rows x 256 cols bf16 -> LDS As[32][264]
DEV void stageA(const bf16* __restrict__ src, short* __restrict__ As, int tid) {
  const int r = tid >> 3, c0 = (tid & 7)*32;
#pragma unroll
  for (int i = 0; i < 4; ++i) {
    short8 v = *(const short8*)&src[(size_t)r*CD + c0 + i*8];
    *(short8*)&As[r*264 + c0 + i*8] = v;
  }
}

// C[p=32][c=256] = A[32][256] x W^T via MFMA with depth-1 prefetch on A(LDS) and B(global)
DEV void mfma_core_pf(const short* __restrict__ As, const short* __restrict__ PKg,
                      int w, int lane, float4v acc[2][4]) {
  const int xb = lane & 15, quad = lane >> 4;
  const short* base = PKg + (size_t)w*4*8*512 + lane*8;
  short8 bcur[4];
#pragma unroll
  for (int nti = 0; nti < 4; ++nti) bcur[nti] = *(const short8*)&base[(size_t)nti*8*512];
  short8 a0 = *(const short8*)&As[xb*264 + quad*8];
  short8 a1 = *(const short8*)&As[(16+xb)*264 + quad*8];
#pragma unroll
  for (int ch = 0; ch < 8; ++ch) {
    const int chn = (ch + 1) & 7;
    short8 bnxt[4];
#pragma unroll
    for (int nti = 0; nti < 4; ++nti) bnxt[nti] = *(const short8*)&base[(size_t)(nti*8 + chn)*512];
    short8 a0n = *(const short8*)&As[xb*264 + chn*32 + quad*8];
    short8 a1n = *(const short8*)&As[(16+xb)*264 + chn*32 + quad*8];
#pragma unroll
    for (int nti = 0; nti < 4; ++nti) {
      acc[0][nti] = __builtin_amdgcn_mfma_f32_16x16x32_bf16(a0, bcur[nti], acc[0][nti], 0, 0, 0);
      acc[1][nti] = __builtin_amdgcn_mfma_f32_16x16x32_bf16(a1, bcur[nti], acc[1][nti], 0, 0, 0);
    }
#pragma unroll
    for (int nti = 0; nti < 4; ++nti) bcur[nti] = bnxt[nti];
    a0 = a0n; a1 = a1n;
  }
}

// ---------------- prep kernels ----------------

__global__ __launch_bounds__(256) void k_init(const void* __restrict__ f, float* __restrict__ ws) {
  const int bf = get_bf(ws);
  const int b = blockIdx.x;
  const int n = b >> 10, p = b & 1023;
  const int c = threadIdx.x;
  bf16* fb = (bf16*)(ws + OF_FEATB);
  fb[(size_t)b*CD + c] = f2bf(LD(f, ((size_t)n*CD + c)*PP + p, bf));
}

__global__ __launch_bounds__(256) void k_qh(const void* __restrict__ emb, const void* __restrict__ qw,
                                            const void* __restrict__ qb, const void* __restrict__ ipw,
                                            const void* __restrict__ ipb, float* __restrict__ ws) {
  const int bf = get_bf(ws);
  const int b = blockIdx.x, s = b / NB, n = b % NB;
  const int o = threadIdx.x;
  __shared__ float se[EMBD];
  __shared__ float sq[CD];
  for (int i = o; i < EMBD; i += CD) se[i] = LD(emb, ((size_t)n*SEQL + s)*EMBD + i, bf);
  __syncthreads();
  float a = LD(qb, o, bf);
  if (bf) {
    const bf16* wr = (const bf16*)qw + (size_t)o*EMBD;
    for (int c = 0; c < EMBD; ++c) a += se[c]*bf2f(wr[c]);
  } else {
    const float* wr = (const float*)qw + (size_t)o*EMBD;
    for (int c = 0; c < EMBD; ++c) a += se[c]*wr[c];
  }
  sq[o] = fmaxf(a, 0.f);
  __syncthreads();
  float a2 = LD(ipb, o, bf);
  if (bf) {
    const bf16* wq = (const bf16*)ipw + (size_t)o*CD;
    for (int c = 0; c < CD; ++c) a2 += sq[c]*bf2f(wq[c]);
  } else {
    const float* wq = (const float*)ipw + (size_t)o*CD;
    for (int c = 0; c < CD; ++c) a2 += sq[c]*wq[c];
  }
  ws[OF_QH + ((size_t)s*NB + n)*CD + o] = a2;
}

__global__ __launch_bounds__(256) void k_wregion(const void* __restrict__ mw, float* __restrict__ ws) {
  const int bf = get_bf(ws);
  const int gid = blockIdx.x*256 + threadIdx.x;
  const int c = gid & (HND-1);
  const int o = (gid >> 9) & (CD-1);
  const int r = gid >> 17;
  const int ry = r/3, rx = r%3;
  float s = 0.f;
  for (int dy = 0; dy < 3; ++dy) {
    if (ry == 0 && dy == 0) continue;
    if (ry == 2 && dy == 2) continue;
    for (int dx = 0; dx < 3; ++dx) {
      if (rx == 0 && dx == 0) continue;
      if (rx == 2 && dx == 2) continue;
      s += LD(mw, ((size_t)o*CIN + 264 + c)*9 + dy*3 + dx, bf);
    }
  }
  ws[OF_WRG + gid] = s;
}

__global__ __launch_bounds__(256) void k_hnw(const void* __restrict__ hn, float* __restrict__ ws) {
  const int bf = get_bf(ws);
  const int b = blockIdx.x, r = b / NB, n = b % NB;
  const int o = threadIdx.x;
  __shared__ float sh[HND];
  for (int i = o; i < HND; i += CD) sh[i] = LD(hn, (size_t)n*HND + i, bf);
  __syncthreads();
  const float* wr = ws + OF_WRG + ((size_t)r*CD + o)*HND;
  float a = 0.f;
  for (int c = 0; c < HND; ++c) a += sh[c]*wr[c];
  ws[OF_HNW + ((size_t)r*NB + n)*CD + o] = a;
}

DEV float spat(int c, int yy, int xx) {
  switch (c) {
    case 0: return xx*(1.f/16) - 1.f;
    case 1: return yy*(1.f/16) - 1.f;
    case 2: return (xx+1)*(1.f/16) - 1.f;
    case 3: return (yy+1)*(1.f/16) - 1.f;
    case 4: return (xx+0.5f)*(1.f/16) - 1.f;
    case 5: return (yy+0.5f)*(1.f/16) - 1.f;
    default: return 1.f/32;
  }
}

__global__ __launch_bounds__(256) void k_sconv(const void* __restrict__ mw, float* __restrict__ ws) {
  const int bf = get_bf(ws);
  const int p = blockIdx.x, o = threadIdx.x;
  const int y = p >> 5, x = p & 31;
  float a = 0.f;
  for (int c = 0; c < 8; ++c)
    for (int dy = 0; dy < 3; ++dy) {
      int yy = y + dy - 1; if ((unsigned)yy >= 32u) continue;
      for (int dx = 0; dx < 3; ++dx) {
        int xx = x + dx - 1; if ((unsigned)xx >= 32u) continue;
        a += LD(mw, ((size_t)o*CIN + 256 + c)*9 + dy*3 + dx, bf) * spat(c, yy, xx);
      }
    }
  ws[OF_SCV + (size_t)p*CD + o] = a;
}

// conv feat weights -> MFMA A-frag order: AW[it=tap*8+ch][mt][lane][8]
__global__ __launch_bounds__(256) void k_wpack(const void* __restrict__ mw, float* __restrict__ ws) {
  const int bf = get_bf(ws);
  const int idx = blockIdx.x*256 + threadIdx.x;
  const int j = idx & 7;
  const int lane = (idx >> 3) & 63;
  const int mt = (idx >> 9) & 15;
  const int ch = (idx >> 13) & 7;
  const int tap = idx >> 16;
  const int o = mt*16 + (lane & 15);
  const int c = ch*32 + (lane >> 4)*8 + j;
  bf16* aw = (bf16*)(ws + OF_AW);
  aw[idx] = f2bf(LD(mw, ((size_t)o*CIN + c)*9 + tap, bf));
}

// linear weights -> MFMA B-frag order: PK[g][nt][ch][lane][8]; g: 0=Wk 1=Wv 2=Wo 3=W1 4=W2
__global__ __launch_bounds__(256) void k_wpackB(const void* __restrict__ ipw, const void* __restrict__ opw,
                                                const void* __restrict__ l1w, const void* __restrict__ l2w,
                                                float* __restrict__ ws) {
  const int bf = get_bf(ws);
  const int idx = blockIdx.x*256 + threadIdx.x;
  const int j = idx & 7;
  const int lane = (idx >> 3) & 63;
  const int ch = (idx >> 9) & 7;
  const int nt = (idx >> 12) & 15;
  const int g = idx >> 16;
  const int o = nt*16 + (lane & 15);
  const int k = ch*32 + (lane >> 4)*8 + j;
  float v;
  switch (g) {
    case 0: v = LD(ipw, ((size_t)(256 + o))*CD + k, bf); break;
    case 1: v = LD(ipw, ((size_t)(512 + o))*CD + k, bf); break;
    case 2: v = LD(opw, (size_t)o*CD + k, bf);           break;
    case 3: v = LD(l1w, (size_t)o*CD + k, bf);           break;
    default: v = LD(l2w, (size_t)o*CD + k, bf);          break;
  }
  ((bf16*)(ws + OF_PK))[idx] = f2bf(v);
}

// ---------------- per-step kernels ----------------

// FUSED conv+LN+KV, 512 blocks x 256 thr, block=(n,y). LDS 53,856B -> 3 blocks/CU.
// union: phase1 Xs[3][34][264] bf16 (13464 fl); phase2 tile[256][33]+red (9024 fl) + AsT[32][264] (4224 fl)
__global__ __launch_bounds__(256) void k_convkv(const void* __restrict__ mg, const void* __restrict__ mbv,
                                                const void* __restrict__ ipb, float* __restrict__ ws) {
  __shared__ float smem[13464];
  short* Xs = (short*)smem;
  float* tile = smem;
  float* red  = smem + 8448;
  short* AsT  = (short*)(smem + 9024);
  const int bfv = get_bf(ws);
  const int b = blockIdx.x, n = b >> 5, y = b & 31;
  const int tid = threadIdx.x;
  const int w = tid >> 6, lane = tid & 63;
  const int xb = lane & 15, quad = lane >> 4;
  const bf16* fb = (const bf16*)(ws + OF_FEATB);

  // ---- stage rows y-1..y+1 zero-padded, transposed: Xs[r][1+x][c] ----
  const short8 zero8 = {0,0,0,0,0,0,0,0};
  if (tid < 192) {
    const int r = tid >> 6, xp = ((tid >> 5) & 1) * 33, c0 = (tid & 31)*8;
    *(short8*)&Xs[(r*34 + xp)*264 + c0] = zero8;
  }
#pragma unroll
  for (int u = 0; u < 12; ++u) {
    const int lin = u*256 + tid;
    const int cgrp = lin & 31, xl = (lin >> 5) & 31, r = lin >> 10;
    const int row = y + r - 1;
    short8 v = zero8;
    if ((unsigned)row < 32u)
      v = *(const short8*)&fb[((size_t)(n*PP + row*32 + xl))*CD + cgrp*8];
    *(short8*)&Xs[(r*34 + 1 + xl)*264 + cgrp*8] = v;
  }
  __syncthreads();

  // ---- conv MFMA K-loop (72 iters), compiler-scheduled window ----
  float4v acc[4][2];
#pragma unroll
  for (int mti = 0; mti < 4; ++mti) { acc[mti][0] = (float4v)0.f; acc[mti][1] = (float4v)0.f; }
  const bf16* AW = (const bf16*)(ws + OF_AW);
#pragma unroll 8
  for (int it = 0; it < 72; ++it) {
    const int tap = it >> 3, ch = it & 7;
    const int dy = tap/3, dx = tap - dy*3;
    short8 b0 = *(const short8*)&Xs[(dy*34 + xb + dx)*264 + ch*32 + quad*8];
    short8 b1 = *(const short8*)&Xs[(dy*34 + 16 + xb + dx)*264 + ch*32 + quad*8];
    const bf16* ap = AW + (((size_t)it*16 + w*4)*64 + lane)*8;
#pragma unroll
    for (int mti = 0; mti < 4; ++mti) {
      short8 a = *(const short8*)&ap[(size_t)mti*512];
      acc[mti][0] = __builtin_amdgcn_mfma_f32_16x16x32_bf16(a, b0, acc[mti][0], 0, 0, 0);
      acc[mti][1] = __builtin_amdgcn_mfma_f32_16x16x32_bf16(a, b1, acc[mti][1], 0, 0, 0);
    }
  }
  __syncthreads();   // Xs dead; tile region live

  // ---- tile[o][x] <- frags ----
#pragma unroll
  for (int mti = 0; mti < 4; ++mti)
#pragma unroll
    for (int nt = 0; nt < 2; ++nt)
#pragma unroll
      for (int r = 0; r < 4; ++r)
        tile[((w*4 + mti)*16 + quad*4 + r)*33 + nt*16 + xb] = acc[mti][nt][r];
  __syncthreads();

  // ---- + static terms, relu ----
  const int o = tid;
  {
    const int ry = (y == 0) ? 0 : ((y == 31) ? 2 : 1);
    const float* hnw = ws + OF_HNW;
    const float bl = hnw[((size_t)(ry*3+0)*NB + n)*CD + o];
    const float bm = hnw[((size_t)(ry*3+1)*NB + n)*CD + o];
    const float br = hnw[((size_t)(ry*3+2)*NB + n)*CD + o];
    const float* sc = ws + OF_SCV + (size_t)(y*32)*CD + o;
#pragma unroll
    for (int x = 0; x < 32; ++x) {
      float v = tile[o*33 + x] + sc[(size_t)x*CD] + (x == 0 ? bl : (x == 31 ? br : bm));
      tile[o*33 + x] = fmaxf(v, 0.f);
    }
  }
  __syncthreads();
  ln_reduce(tile, red, tid);
  {
    const float g = LD(mg, o, bfv), bb = LD(mbv, o, bfv);
    bf16* tp = (bf16*)(ws + OF_TB) + ((size_t)n*PP + (size_t)y*32)*CD + o;
#pragma unroll
    for (int x = 0; x < 32; ++x) {
      const bf16 tv = f2bf((tile[o*33 + x] - red[512 + x]) * red[544 + x] * g + bb);
      tp[(size_t)x*CD] = tv;                  // global (outproj residual)
      AsT[x*264 + o] = *(const short*)&tv;    // LDS A-tile for K/V
    }
  }
  __syncthreads();

  // ---- K and V projections from AsT ----
  const short* PK = (const short*)(ws + OF_PK);
  const int p0 = y << 5;
#pragma unroll 1
  for (int G = 0; G < 2; ++G) {
    float4v ac2[2][4];
#pragma unroll
    for (int mt = 0; mt < 2; ++mt)
#pragma unroll
      for (int nti = 0; nti < 4; ++nti) ac2[mt][nti] = (float4v)0.f;
    mfma_core_pf(AsT, PK + (size_t)G*65536, w, lane, ac2);
    bf16* dst = (bf16*)(ws + (G ? OF_VVB : OF_KHB)) + ((size_t)n*PP + p0)*CD;
#pragma unroll
    for (int nti = 0; nti < 4; ++nti) {
      const int c = (w*4 + nti)*16 + xb;
      const float bias = LD(ipb, (size_t)(G+1)*256 + c, bfv);
#pragma unroll
      for (int mt = 0; mt < 2; ++mt)
#pragma unroll
        for (int r = 0; r < 4; ++r)
          dst[(size_t)(mt*16 + quad*4 + r)*CD + c] = f2bf(ac2[mt][nti][r] + bias);
    }
  }
}

// cross-batch attention: one wave per (p, h); bf16 K/V, fp32 math
__global__ __launch_bounds__(64) void k_attn(int s, float* __restrict__ ws) {
  __shared__ float SQ[16*132], SK[16*132], SV[16*132], SA[16*20];
  const int p = blockIdx.x >> 1, h = blockIdx.x & 1;
  const int lane = threadIdx.x;
  const bf16* khb = (const bf16*)(ws + OF_KHB);
  const bf16* vvb = (const bf16*)(ws + OF_VVB);
  for (int i = lane; i < 16*128; i += 64) {
    const int l = i >> 7, d = i & 127;
    SQ[l*132 + d] = ws[OF_QH + ((size_t)(s*NB + l))*CD + h*128 + d];
    SK[l*132 + d] = bf2f(khb[((size_t)l*PP + p)*CD + h*128 + d]);
    SV[l*132 + d] = bf2f(vvb[((size_t)l*PP + p)*CD + h*128 + d]);
  }
  __syncthreads();
  const int l = lane >> 2, mg = lane & 3;
  float sc[4];
#pragma unroll
  for (int j = 0; j < 4; ++j) {
    const int m = mg*4 + j;
    float a = 0.f;
    for (int d4 = 0; d4 < 128; d4 += 4) {
      float4 q = *(const float4*)&SQ[l*132 + d4];
      float4 k = *(const float4*)&SK[m*132 + d4];
      a += q.x*k.x + q.y*k.y + q.z*k.z + q.w*k.w;
    }
    sc[j] = a * 0.08838834764831845f;
  }
  float mx = fmaxf(fmaxf(sc[0], sc[1]), fmaxf(sc[2], sc[3]));
  mx = fmaxf(mx, __shfl_xor(mx, 1, 64));
  mx = fmaxf(mx, __shfl_xor(mx, 2, 64));
  float sum = 0.f;
#pragma unroll
  for (int j = 0; j < 4; ++j) { sc[j] = __expf(sc[j] - mx); sum += sc[j]; }
  sum += __shfl_xor(sum, 1, 64);
  sum += __shfl_xor(sum, 2, 64);
  const float inv = 1.f / sum;
#pragma unroll
  for (int j = 0; j < 4; ++j) SA[l*20 + mg*4 + j] = sc[j]*inv;
  __syncthreads();
  float oa[32];
#pragma unroll
  for (int d = 0; d < 32; ++d) oa[d] = 0.f;
  for (int m = 0; m < 16; ++m) {
    const float a = SA[l*20 + m];
#pragma unroll
    for (int d4 = 0; d4 < 8; ++d4) {
      float4 v = *(const float4*)&SV[m*132 + mg*32 + d4*4];
      oa[d4*4+0] += a*v.x; oa[d4*4+1] += a*v.y; oa[d4*4+2] += a*v.z; oa[d4*4+3] += a*v.w;
    }
  }
  bf16* dst = (bf16*)(ws + OF_AOB) + ((size_t)l*PP + p)*CD + h*128 + mg*32;
#pragma unroll
  for (int d = 0; d < 32; ++d) dst[d] = f2bf(oa[d]);
}

// FUSED outproj+LN+lin1+lin2+LN+commit. LDS 52,992B -> 3 blocks/CU.
// union region T (9024 fl = tile+red): also holds ao-staging then f2a (as shorts, 4224 fl each).
// AsF (fea) separate at smem+9024 (4224 fl).
__global__ __launch_bounds__(256) void k_oplin(const void* __restrict__ opb, const void* __restrict__ ng,
                                               const void* __restrict__ nbv, const void* __restrict__ l1b,
                                               const void* __restrict__ l2b, const void* __restrict__ nfg,
                                               const void* __restrict__ nfb, const int* __restrict__ words,
                                               int s, float* __restrict__ ws) {
  __shared__ float smem[13248];
  float* tile = smem;
  float* red  = smem + 8448;
  short* AsT  = (short*)smem;              // ao staging, later f2a (aliases tile)
  short* AsF  = (short*)(smem + 9024);     // fea
  const int bf = get_bf(ws);
  const int b = blockIdx.x, n = b >> 5, p0 = (b & 31) << 5;
  const int tid = threadIdx.x, w = tid >> 6, lane = tid & 63;
  const int xb = lane & 15, quad = lane >> 4;
  const int o = tid;
  const short* PK = (const short*)(ws + OF_PK);

  // ---- outproj ----
  stageA((const bf16*)(ws + OF_AOB) + ((size_t)n*PP + p0)*CD, AsT, tid);
  __syncthreads();
  {
    float4v acc[2][4];
#pragma unroll
    for (int mt = 0; mt < 2; ++mt)
#pragma unroll
      for (int nti = 0; nti < 4; ++nti) acc[mt][nti] = (float4v)0.f;
    mfma_core_pf(AsT, PK + (size_t)2*65536, w, lane, acc);
    __syncthreads();   // all MFMA reads of ao done before tile overwrites it
#pragma unroll
    for (int nti = 0; nti < 4; ++nti)
#pragma unroll
      for (int mt = 0; mt < 2; ++mt)
#pragma unroll
        for (int r = 0; r < 4; ++r)
          tile[((w*4 + nti)*16 + xb)*33 + mt*16 + quad*4 + r] = acc[mt][nti][r];
  }
  __syncthreads();
  {
    const float bo = LD(opb, o, bf);
    const bf16* tb = (const bf16*)(ws + OF_TB) + ((size_t)n*PP + p0)*CD + o;
#pragma unroll
    for (int x = 0; x < 32; ++x)
      tile[o*33 + x] += bo + bf2f(tb[(size_t)x*CD]);
  }
  __syncthreads();
  ln_reduce(tile, red, tid);
  {
    const float g = LD(ng, o, bf), bb = LD(nbv, o, bf);
#pragma unroll
    for (int x = 0; x < 32; ++x) {
      const bf16 fv = f2bf((tile[o*33 + x] - red[512 + x]) * red[544 + x] * g + bb);
      AsF[x*264 + o] = *(const short*)&fv;
    }
  }
  __syncthreads();   // AsF ready; tile now dead

  // ---- lin1: f2a -> T region (tile dead) ----
  {
    float4v acc[2][4];
#pragma unroll
    for (int mt = 0; mt < 2; ++mt)
#pragma unroll
      for (int nti = 0; nti < 4; ++nti) acc[mt][nti] = (float4v)0.f;
    mfma_core_pf(AsF, PK + (size_t)3*65536, w, lane, acc);
#pragma unroll
    for (int nti = 0; nti < 4; ++nti) {
      const int c = (w*4 + nti)*16 + xb;
      const float bias = LD(l1b, c, bf);
#pragma unroll
      for (int mt = 0; mt < 2; ++mt)
#pragma unroll
        for (int r = 0; r < 4; ++r) {
          const bf16 fv = f2bf(fmaxf(acc[mt][nti][r] + bias, 0.f));
          AsT[(mt*16 + quad*4 + r)*264 + c] = *(const short*)&fv;
        }
    }
  }
  __syncthreads();

  // ---- lin2 + LN + conditional commit ----
  {
    float4v acc[2][4];
#pragma unroll
    for (int mt = 0; mt < 2; ++mt)
#pragma unroll
      for (int nti = 0; nti < 4; ++nti) acc[mt][nti] = (float4v)0.f;
    mfma_core_pf(AsT, PK + (size_t)4*65536, w, lane, acc);
    __syncthreads();   // f2a reads done before tile overwrites it
#pragma unroll
    for (int nti = 0; nti < 4; ++nti)
#pragma unroll
      for (int mt = 0; mt < 2; ++mt)
#pragma unroll
        for (int r = 0; r < 4; ++r)
          tile[((w*4 + nti)*16 + xb)*33 + mt*16 + quad*4 + r] = acc[mt][nti][r];
  }
  __syncthreads();
  {
    const float bb = LD(l2b, o, bf);
#pragma unroll
    for (int x = 0; x < 32; ++x) {
      bf16 fv; *(short*)&fv = AsF[x*264 + o];
      tile[o*33 + x] += bb + bf2f(fv);
    }
  }
  __syncthreads();
  ln_reduce(tile, red, tid);
  if (words[s] != 0) {
    const float g = LD(nfg, o, bf), b2 = LD(nfb, o, bf);
    bf16* fbd = (bf16*)(ws + OF_FEATB) + ((size_t)n*PP + p0)*CD + o;
#pragma unroll
    for (int x = 0; x < 32; ++x)
      fbd[(size_t)x*CD] = f2bf((tile[o*33 + x] - red[512 + x]) * red[544 + x] * g + b2);
  }
}

// output [n][c][p] from bf16 feat [n][p][c]
__global__ __launch_bounds__(256) void k_final(const float* __restrict__ ws, void* __restrict__ out) {
  const int bf = get_bf(ws);
  const size_t i = (size_t)blockIdx.x*256 + threadIdx.x;
  const int n = (int)(i >> 18), c = (int)((i >> 10) & 255), p = (int)(i & 1023);
  const bf16* fb = (const bf16*)(ws + OF_FEATB);
  float v = bf2f(fb[((size_t)(n*PP + p))*CD + c]);
  if (bf) ((bf16*)out)[i] = f2bf(v);
  else    ((float*)out)[i] = v;
}

extern "C" void kernel_launch(void* const* d_in, const int* in_sizes, int n_in,
                              void* d_out, int out_size, void* d_ws, size_t ws_size,
                              hipStream_t stream) {
  (void)in_sizes; (void)n_in; (void)out_size; (void)ws_size;
  const void* hn      = d_in[1];
  const void* feature = d_in[2];
  const void* emb     = d_in[3];
  const int*  words   = (const int*)d_in[4];
  const void* qw  = d_in[5];
  const void* qb  = d_in[6];
  const void* mw  = d_in[7];
  const void* mg  = d_in[8];
  const void* mb  = d_in[9];
  const void* ipw = d_in[10];
  const void* ipb = d_in[11];
  const void* opw = d_in[12];
  const void* opb = d_in[13];
  const void* ng  = d_in[14];
  const void* nb  = d_in[15];
  const void* l1w = d_in[16];
  const void* l1b = d_in[17];
  const void* l2w = d_in[18];
  const void* l2b = d_in[19];
  const void* nfg = d_in[20];
  const void* nfb = d_in[21];
  float* ws = (float*)d_ws;

  k_detect<<<1, 64, 0, stream>>>(mg, ws);
  k_init<<<NB*PP, 256, 0, stream>>>(feature, ws);
  k_qh<<<SEQL*NB, 256, 0, stream>>>(emb, qw, qb, ipw, ipb, ws);
  k_wregion<<<(9*CD*HND)/256, 256, 0, stream>>>(mw, ws);
  k_hnw<<<9*NB, 256, 0, stream>>>(hn, ws);
  k_sconv<<<PP, 256, 0, stream>>>(mw, ws);
  k_wpack<<<(9*8*16*64*8)/256, 256, 0, stream>>>(mw, ws);
  k_wpackB<<<(5*65536)/256, 256, 0, stream>>>(ipw, opw, l1w, l2w, ws);

  for (int s = 0; s < SEQL; ++s) {
    k_convkv<<<NB*32, 256, 0, stream>>>(mg, mb, ipb, ws);
    k_attn<<<PP*2, 64, 0, stream>>>(s, ws);
    k_oplin<<<NB*32, 256, 0, stream>>>(opb, ng, nb, l1b, l2b, nfg, nfb, words, s, ws);
  }
  k_final<<<NB*CD*PP/256, 256, 0, stream>>>(ws, (void*)d_out);
}

// Round 8
// 1802.817 us; speedup vs baseline: 1.3141x; 1.3141x over previous
//
#include <hip/hip_runtime.h>
#include <hip/hip_bf16.h>
#include <cstddef>

typedef __hip_bfloat16 bf16;
typedef short short8 __attribute__((ext_vector_type(8)));
typedef float float4v __attribute__((ext_vector_type(4)));
#define DEV static __device__ __forceinline__

constexpr int NB = 16;     // batch
constexpr int SEQL = 20;
constexpr int CD = 256;    // VD
constexpr int PP = 1024;   // 32*32
constexpr int HND = 512;
constexpr int EMBD = 300;
constexpr int CIN = 776;   // 256 + 8 + 512

// ---- workspace layout (float element offsets); bf16 buffers are [n][p][c] ----
constexpr size_t SZB = (size_t)NB * PP * CD / 2;             // floats per bf16 NPC buffer
constexpr size_t OF_FEATB = 0;                               // running feature (bf16)
constexpr size_t OF_TB   = 1*SZB;                            // t (bf16)
constexpr size_t OF_KHB  = 2*SZB;                            // kh (bf16)
constexpr size_t OF_VVB  = 3*SZB;                            // vv (bf16)
constexpr size_t OF_AOB  = 4*SZB;                            // attn out (bf16)
constexpr size_t OF_QH   = 7*SZB;                            // qh [s][n][c] fp32
constexpr size_t OF_HNW  = OF_QH  + (size_t)SEQL*NB*CD;      // hnW [r][n][o] fp32
constexpr size_t OF_SCV  = OF_HNW + (size_t)9*NB*CD;         // sconv [p][o] fp32
constexpr size_t OF_WRG  = OF_SCV + (size_t)PP*CD;           // W_region [r][o][c] fp32
constexpr size_t OF_AW   = OF_WRG + (size_t)9*CD*HND;        // conv W A-frags (589,824 bf16)
constexpr size_t OF_PK   = OF_AW  + (size_t)294912;          // linear W B-frags: 5 x 65,536 bf16
constexpr size_t OF_FLAG = OF_PK  + (size_t)163840;          // dtype flag

DEV float bf2f(bf16 v) { return __bfloat162float(v); }
DEV bf16 f2bf(float v) { return __float2bfloat16(v); }

DEV float LD(const void* p, size_t i, int bf) {
  return bf ? __bfloat162float(((const bf16*)p)[i]) : ((const float*)p)[i];
}
DEV int get_bf(const float* ws) { return ((const int*)ws)[OF_FLAG]; }

__global__ void k_detect(const void* g, float* ws) {
  if (threadIdx.x == 0 && blockIdx.x == 0) {
    unsigned w = *(const unsigned*)g;
    ((int*)ws)[OF_FLAG] = ((w & 0xFFFFu) != 0u) ? 1 : 0;
  }
}

// LN reduction, 512 threads: tile[o][x] stride 33; red[1024+x]=mean, red[1056+x]=rstd
DEV void ln_reduce512(const float* tile, float* red, int tid) {
  const int x = tid & 31, seg = tid >> 5;   // 16 segs of 16 channels
  float s = 0.f, sq = 0.f;
#pragma unroll
  for (int i = 0; i < 16; ++i) {
    float v = tile[(seg*16 + i)*33 + x];
    s += v; sq += v*v;
  }
  red[seg*32 + x] = s;
  red[512 + seg*32 + x] = sq;
  __syncthreads();
  if (tid < 32) {
    float ts = 0.f, tq = 0.f;
#pragma unroll
    for (int g = 0; g < 16; ++g) { ts += red[g*32 + tid]; tq += red[512 + g*32 + tid]; }
    float m = ts * (1.f/CD);
    float var = tq * (1.f/CD) - m*m;
    red[1024 + tid] = m;
    red[1056 + tid] = 1.f / sqrtf(var + 1e-5f);
  }
  __syncthreads();
}

// stage 32 rows x 256 cols bf16 -> LDS As[32][264], 512 threads
DEV void stageA512(const bf16* __restrict__ src, short* __restrict__ As, int tid) {
  const int r = tid >> 4, c0 = (tid & 15)*16;
#pragma unroll
  for (int i = 0; i < 2; ++i) {
    short8 v = *(const short8*)&src[(size_t)r*CD + c0 + i*8];
    *(short8*)&As[r*264 + c0 + i*8] = v;
  }
}

// 512-thr linear core: C[p=32][c=256] = A[32][256] x W^T; wave w owns c-tiles {2w,2w+1}, row-tiles {0,1}
DEV void mfma_core512(const short* __restrict__ As, const short* __restrict__ PKg,
                      int w, int lane, float4v acc[2][2]) {
  const int xb = lane & 15, quad = lane >> 4;
  const short* base = PKg + lane*8;
#pragma unroll
  for (int ch = 0; ch < 8; ++ch) {
    short8 a0 = *(const short8*)&As[xb*264 + ch*32 + quad*8];
    short8 a1 = *(const short8*)&As[(16+xb)*264 + ch*32 + quad*8];
    short8 b0 = *(const short8*)&base[(size_t)((w*2+0)*8 + ch)*512];
    short8 b1 = *(const short8*)&base[(size_t)((w*2+1)*8 + ch)*512];
    acc[0][0] = __builtin_amdgcn_mfma_f32_16x16x32_bf16(a0, b0, acc[0][0], 0, 0, 0);
    acc[0][1] = __builtin_amdgcn_mfma_f32_16x16x32_bf16(a0, b1, acc[0][1], 0, 0, 0);
    acc[1][0] = __builtin_amdgcn_mfma_f32_16x16x32_bf16(a1, b0, acc[1][0], 0, 0, 0);
    acc[1][1] = __builtin_amdgcn_mfma_f32_16x16x32_bf16(a1, b1, acc[1][1], 0, 0, 0);
  }
}

// ---------------- prep kernels ----------------

__global__ __launch_bounds__(256) void k_init(const void* __restrict__ f, float* __restrict__ ws) {
  const int bf = get_bf(ws);
  const int b = blockIdx.x;
  const int n = b >> 10, p = b & 1023;
  const int c = threadIdx.x;
  bf16* fb = (bf16*)(ws + OF_FEATB);
  fb[(size_t)b*CD + c] = f2bf(LD(f, ((size_t)n*CD + c)*PP + p, bf));
}

__global__ __launch_bounds__(256) void k_qh(const void* __restrict__ emb, const void* __restrict__ qw,
                                            const void* __restrict__ qb, const void* __restrict__ ipw,
                                            const void* __restrict__ ipb, float* __restrict__ ws) {
  const int bf = get_bf(ws);
  const int b = blockIdx.x, s = b / NB, n = b % NB;
  const int o = threadIdx.x;
  __shared__ float se[EMBD];
  __shared__ float sq[CD];
  for (int i = o; i < EMBD; i += CD) se[i] = LD(emb, ((size_t)n*SEQL + s)*EMBD + i, bf);
  __syncthreads();
  float a = LD(qb, o, bf);
  if (bf) {
    const bf16* wr = (const bf16*)qw + (size_t)o*EMBD;
    for (int c = 0; c < EMBD; ++c) a += se[c]*bf2f(wr[c]);
  } else {
    const float* wr = (const float*)qw + (size_t)o*EMBD;
    for (int c = 0; c < EMBD; ++c) a += se[c]*wr[c];
  }
  sq[o] = fmaxf(a, 0.f);
  __syncthreads();
  float a2 = LD(ipb, o, bf);
  if (bf) {
    const bf16* wq = (const bf16*)ipw + (size_t)o*CD;
    for (int c = 0; c < CD; ++c) a2 += sq[c]*bf2f(wq[c]);
  } else {
    const float* wq = (const float*)ipw + (size_t)o*CD;
    for (int c = 0; c < CD; ++c) a2 += sq[c]*wq[c];
  }
  ws[OF_QH + ((size_t)s*NB + n)*CD + o] = a2;
}

__global__ __launch_bounds__(256) void k_wregion(const void* __restrict__ mw, float* __restrict__ ws) {
  const int bf = get_bf(ws);
  const int gid = blockIdx.x*256 + threadIdx.x;
  const int c = gid & (HND-1);
  const int o = (gid >> 9) & (CD-1);
  const int r = gid >> 17;
  const int ry = r/3, rx = r%3;
  float s = 0.f;
  for (int dy = 0; dy < 3; ++dy) {
    if (ry == 0 && dy == 0) continue;
    if (ry == 2 && dy == 2) continue;
    for (int dx = 0; dx < 3; ++dx) {
      if (rx == 0 && dx == 0) continue;
      if (rx == 2 && dx == 2) continue;
      s += LD(mw, ((size_t)o*CIN + 264 + c)*9 + dy*3 + dx, bf);
    }
  }
  ws[OF_WRG + gid] = s;
}

__global__ __launch_bounds__(256) void k_hnw(const void* __restrict__ hn, float* __restrict__ ws) {
  const int bf = get_bf(ws);
  const int b = blockIdx.x, r = b / NB, n = b % NB;
  const int o = threadIdx.x;
  __shared__ float sh[HND];
  for (int i = o; i < HND; i += CD) sh[i] = LD(hn, (size_t)n*HND + i, bf);
  __syncthreads();
  const float* wr = ws + OF_WRG + ((size_t)r*CD + o)*HND;
  float a = 0.f;
  for (int c = 0; c < HND; ++c) a += sh[c]*wr[c];
  ws[OF_HNW + ((size_t)r*NB + n)*CD + o] = a;
}

DEV float spat(int c, int yy, int xx) {
  switch (c) {
    case 0: return xx*(1.f/16) - 1.f;
    case 1: return yy*(1.f/16) - 1.f;
    case 2: return (xx+1)*(1.f/16) - 1.f;
    case 3: return (yy+1)*(1.f/16) - 1.f;
    case 4: return (xx+0.5f)*(1.f/16) - 1.f;
    case 5: return (yy+0.5f)*(1.f/16) - 1.f;
    default: return 1.f/32;
  }
}

__global__ __launch_bounds__(256) void k_sconv(const void* __restrict__ mw, float* __restrict__ ws) {
  const int bf = get_bf(ws);
  const int p = blockIdx.x, o = threadIdx.x;
  const int y = p >> 5, x = p & 31;
  float a = 0.f;
  for (int c = 0; c < 8; ++c)
    for (int dy = 0; dy < 3; ++dy) {
      int yy = y + dy - 1; if ((unsigned)yy >= 32u) continue;
      for (int dx = 0; dx < 3; ++dx) {
        int xx = x + dx - 1; if ((unsigned)xx >= 32u) continue;
        a += LD(mw, ((size_t)o*CIN + 256 + c)*9 + dy*3 + dx, bf) * spat(c, yy, xx);
      }
    }
  ws[OF_SCV + (size_t)p*CD + o] = a;
}

// conv feat weights -> MFMA A-frag order: AW[it=tap*8+ch][mt][lane][8]
__global__ __launch_bounds__(256) void k_wpack(const void* __restrict__ mw, float* __restrict__ ws) {
  const int bf = get_bf(ws);
  const int idx = blockIdx.x*256 + threadIdx.x;
  const int j = idx & 7;
  const int lane = (idx >> 3) & 63;
  const int mt = (idx >> 9) & 15;
  const int ch = (idx >> 13) & 7;
  const int tap = idx >> 16;
  const int o = mt*16 + (lane & 15);
  const int c = ch*32 + (lane >> 4)*8 + j;
  bf16* aw = (bf16*)(ws + OF_AW);
  aw[idx] = f2bf(LD(mw, ((size_t)o*CIN + c)*9 + tap, bf));
}

// linear weights -> MFMA B-frag order: PK[g][nt][ch][lane][8]; g: 0=Wk 1=Wv 2=Wo 3=W1 4=W2
__global__ __launch_bounds__(256) void k_wpackB(const void* __restrict__ ipw, const void* __restrict__ opw,
                                                const void* __restrict__ l1w, const void* __restrict__ l2w,
                                                float* __restrict__ ws) {
  const int bf = get_bf(ws);
  const int idx = blockIdx.x*256 + threadIdx.x;
  const int j = idx & 7;
  const int lane = (idx >> 3) & 63;
  const int ch = (idx >> 9) & 7;
  const int nt = (idx >> 12) & 15;
  const int g = idx >> 16;
  const int o = nt*16 + (lane & 15);
  const int k = ch*32 + (lane >> 4)*8 + j;
  float v;
  switch (g) {
    case 0: v = LD(ipw, ((size_t)(256 + o))*CD + k, bf); break;
    case 1: v = LD(ipw, ((size_t)(512 + o))*CD + k, bf); break;
    case 2: v = LD(opw, (size_t)o*CD + k, bf);           break;
    case 3: v = LD(l1w, (size_t)o*CD + k, bf);           break;
    default: v = LD(l2w, (size_t)o*CD + k, bf);          break;
  }
  ((bf16*)(ws + OF_PK))[idx] = f2bf(v);
}

// ---------------- per-step kernels ----------------

// FUSED conv+LN+KV: 512 blocks x 512 thr, block=(n,y). 16 waves/CU (2 blocks/CU).
// LDS union: phase1 Xs[3][34][264] bf16 (13464 fl); phase2 tile(8448)+red(1088)+AsT(4224) = 13760 fl
__global__ __launch_bounds__(512, 4) void k_convkv(const void* __restrict__ mg, const void* __restrict__ mbv,
                                                   const void* __restrict__ ipb, float* __restrict__ ws) {
  __shared__ float smem[13760];
  short* Xs = (short*)smem;
  float* tile = smem;
  float* red  = smem + 8448;
  short* AsT  = (short*)(smem + 9536);
  const int bfv = get_bf(ws);
  const int b = blockIdx.x, n = b >> 5, y = b & 31;
  const int tid = threadIdx.x;
  const int w = tid >> 6, lane = tid & 63;      // 8 waves
  const int xb = lane & 15, quad = lane >> 4;
  const bf16* fb = (const bf16*)(ws + OF_FEATB);

  // ---- stage rows y-1..y+1 zero-padded, transposed: Xs[r][1+x][c] ----
  const short8 zero8 = {0,0,0,0,0,0,0,0};
  if (tid < 192) {
    const int r = tid >> 6, xp = ((tid >> 5) & 1) * 33, c0 = (tid & 31)*8;
    *(short8*)&Xs[(r*34 + xp)*264 + c0] = zero8;
  }
#pragma unroll
  for (int u = 0; u < 6; ++u) {
    const int lin = u*512 + tid;
    const int cgrp = lin & 31, xl = (lin >> 5) & 31, r = lin >> 10;
    const int row = y + r - 1;
    short8 v = zero8;
    if ((unsigned)row < 32u)
      v = *(const short8*)&fb[((size_t)(n*PP + row*32 + xl))*CD + cgrp*8];
    *(short8*)&Xs[(r*34 + 1 + xl)*264 + cgrp*8] = v;
  }
  __syncthreads();

  // ---- conv MFMA K-loop: wave w owns o-tiles {2w, 2w+1}, both x-halves ----
  float4v acc[2][2];
#pragma unroll
  for (int mt = 0; mt < 2; ++mt) { acc[mt][0] = (float4v)0.f; acc[mt][1] = (float4v)0.f; }
  const bf16* AW = (const bf16*)(ws + OF_AW);
#pragma unroll 8
  for (int it = 0; it < 72; ++it) {
    const int tap = it >> 3, ch = it & 7;
    const int dy = tap/3, dx = tap - dy*3;
    short8 b0 = *(const short8*)&Xs[(dy*34 + xb + dx)*264 + ch*32 + quad*8];
    short8 b1 = *(const short8*)&Xs[(dy*34 + 16 + xb + dx)*264 + ch*32 + quad*8];
    const bf16* ap = AW + (((size_t)it*16 + w*2)*64 + lane)*8;
    short8 a0 = *(const short8*)&ap[0];
    short8 a1 = *(const short8*)&ap[512];
    acc[0][0] = __builtin_amdgcn_mfma_f32_16x16x32_bf16(a0, b0, acc[0][0], 0, 0, 0);
    acc[0][1] = __builtin_amdgcn_mfma_f32_16x16x32_bf16(a0, b1, acc[0][1], 0, 0, 0);
    acc[1][0] = __builtin_amdgcn_mfma_f32_16x16x32_bf16(a1, b0, acc[1][0], 0, 0, 0);
    acc[1][1] = __builtin_amdgcn_mfma_f32_16x16x32_bf16(a1, b1, acc[1][1], 0, 0, 0);
  }
  __syncthreads();   // Xs dead

  // ---- tile[o][x] <- frags ----
#pragma unroll
  for (int mt = 0; mt < 2; ++mt)
#pragma unroll
    for (int xh = 0; xh < 2; ++xh)
#pragma unroll
      for (int r = 0; r < 4; ++r)
        tile[((w*2 + mt)*16 + quad*4 + r)*33 + xh*16 + xb] = acc[mt][xh][r];
  __syncthreads();

  // ---- + static terms, relu (512 thr: o = tid&255, half = tid>>8) ----
  const int o = tid & 255, half = tid >> 8;
  {
    const int ry = (y == 0) ? 0 : ((y == 31) ? 2 : 1);
    const float* hnw = ws + OF_HNW;
    const float bl = hnw[((size_t)(ry*3+0)*NB + n)*CD + o];
    const float bm = hnw[((size_t)(ry*3+1)*NB + n)*CD + o];
    const float br = hnw[((size_t)(ry*3+2)*NB + n)*CD + o];
    const float* sc = ws + OF_SCV + (size_t)(y*32)*CD + o;
#pragma unroll
    for (int xi = 0; xi < 16; ++xi) {
      const int x = half*16 + xi;
      float v = tile[o*33 + x] + sc[(size_t)x*CD] + (x == 0 ? bl : (x == 31 ? br : bm));
      tile[o*33 + x] = fmaxf(v, 0.f);
    }
  }
  __syncthreads();
  ln_reduce512(tile, red, tid);
  {
    const float g = LD(mg, o, bfv), bb = LD(mbv, o, bfv);
    bf16* tp = (bf16*)(ws + OF_TB) + ((size_t)n*PP + (size_t)y*32)*CD + o;
#pragma unroll
    for (int xi = 0; xi < 16; ++xi) {
      const int x = half*16 + xi;
      const bf16 tv = f2bf((tile[o*33 + x] - red[1024 + x]) * red[1056 + x] * g + bb);
      tp[(size_t)x*CD] = tv;                  // global (outproj residual)
      AsT[x*264 + o] = *(const short*)&tv;    // LDS A-tile for K/V
    }
  }
  __syncthreads();

  // ---- K and V projections from AsT: wave w owns c-tiles {2w, 2w+1} ----
  const short* PK = (const short*)(ws + OF_PK);
  const int p0 = y << 5;
#pragma unroll 1
  for (int G = 0; G < 2; ++G) {
    float4v ac2[2][2];
#pragma unroll
    for (int mt = 0; mt < 2; ++mt) { ac2[mt][0] = (float4v)0.f; ac2[mt][1] = (float4v)0.f; }
    mfma_core512(AsT, PK + (size_t)G*65536, w, lane, ac2);
    bf16* dst = (bf16*)(ws + (G ? OF_VVB : OF_KHB)) + ((size_t)n*PP + p0)*CD;
#pragma unroll
    for (int i = 0; i < 2; ++i) {
      const int c = (w*2 + i)*16 + xb;
      const float bias = LD(ipb, (size_t)(G+1)*256 + c, bfv);
#pragma unroll
      for (int mt = 0; mt < 2; ++mt)
#pragma unroll
        for (int r = 0; r < 4; ++r)
          dst[(size_t)(mt*16 + quad*4 + r)*CD + c] = f2bf(ac2[mt][i][r] + bias);
    }
  }
}

// cross-batch attention: one wave per (p, h); bf16 K/V, fp32 math
__global__ __launch_bounds__(64) void k_attn(int s, float* __restrict__ ws) {
  __shared__ float SQ[16*132], SK[16*132], SV[16*132], SA[16*20];
  const int p = blockIdx.x >> 1, h = blockIdx.x & 1;
  const int lane = threadIdx.x;
  const bf16* khb = (const bf16*)(ws + OF_KHB);
  const bf16* vvb = (const bf16*)(ws + OF_VVB);
  for (int i = lane; i < 16*128; i += 64) {
    const int l = i >> 7, d = i & 127;
    SQ[l*132 + d] = ws[OF_QH + ((size_t)(s*NB + l))*CD + h*128 + d];
    SK[l*132 + d] = bf2f(khb[((size_t)l*PP + p)*CD + h*128 + d]);
    SV[l*132 + d] = bf2f(vvb[((size_t)l*PP + p)*CD + h*128 + d]);
  }
  __syncthreads();
  const int l = lane >> 2, mg = lane & 3;
  float sc[4];
#pragma unroll
  for (int j = 0; j < 4; ++j) {
    const int m = mg*4 + j;
    float a = 0.f;
    for (int d4 = 0; d4 < 128; d4 += 4) {
      float4 q = *(const float4*)&SQ[l*132 + d4];
      float4 k = *(const float4*)&SK[m*132 + d4];
      a += q.x*k.x + q.y*k.y + q.z*k.z + q.w*k.w;
    }
    sc[j] = a * 0.08838834764831845f;
  }
  float mx = fmaxf(fmaxf(sc[0], sc[1]), fmaxf(sc[2], sc[3]));
  mx = fmaxf(mx, __shfl_xor(mx, 1, 64));
  mx = fmaxf(mx, __shfl_xor(mx, 2, 64));
  float sum = 0.f;
#pragma unroll
  for (int j = 0; j < 4; ++j) { sc[j] = __expf(sc[j] - mx); sum += sc[j]; }
  sum += __shfl_xor(sum, 1, 64);
  sum += __shfl_xor(sum, 2, 64);
  const float inv = 1.f / sum;
#pragma unroll
  for (int j = 0; j < 4; ++j) SA[l*20 + mg*4 + j] = sc[j]*inv;
  __syncthreads();
  float oa[32];
#pragma unroll
  for (int d = 0; d < 32; ++d) oa[d] = 0.f;
  for (int m = 0; m < 16; ++m) {
    const float a = SA[l*20 + m];
#pragma unroll
    for (int d4 = 0; d4 < 8; ++d4) {
      float4 v = *(const float4*)&SV[m*132 + mg*32 + d4*4];
      oa[d4*4+0] += a*v.x; oa[d4*4+1] += a*v.y; oa[d4*4+2] += a*v.z; oa[d4*4+3] += a*v.w;
    }
  }
  bf16* dst = (bf16*)(ws + OF_AOB) + ((size_t)l*PP + p)*CD + h*128 + mg*32;
#pragma unroll
  for (int d = 0; d < 32; ++d) dst[d] = f2bf(oa[d]);
}

// FUSED outproj+LN+lin1+lin2+LN+commit: 512 blocks x 512 thr.
// LDS: tile(8448)+red(1088)+AsF(4224) = 13760 fl; AsT (ao, then f2a) aliases tile.
__global__ __launch_bounds__(512, 4) void k_oplin(const void* __restrict__ opb, const void* __restrict__ ng,
                                                  const void* __restrict__ nbv, const void* __restrict__ l1b,
                                                  const void* __restrict__ l2b, const void* __restrict__ nfg,
                                                  const void* __restrict__ nfb, const int* __restrict__ words,
                                                  int s, float* __restrict__ ws) {
  __shared__ float smem[13760];
  float* tile = smem;
  float* red  = smem + 8448;
  short* AsT  = (short*)smem;              // ao staging, later f2a (aliases tile)
  short* AsF  = (short*)(smem + 9536);     // fea
  const int bf = get_bf(ws);
  const int b = blockIdx.x, n = b >> 5, p0 = (b & 31) << 5;
  const int tid = threadIdx.x, w = tid >> 6, lane = tid & 63;
  const int xb = lane & 15, quad = lane >> 4;
  const int o = tid & 255, half = tid >> 8;
  const short* PK = (const short*)(ws + OF_PK);

  // ---- outproj ----
  stageA512((const bf16*)(ws + OF_AOB) + ((size_t)n*PP + p0)*CD, AsT, tid);
  __syncthreads();
  {
    float4v acc[2][2];
#pragma unroll
    for (int mt = 0; mt < 2; ++mt) { acc[mt][0] = (float4v)0.f; acc[mt][1] = (float4v)0.f; }
    mfma_core512(AsT, PK + (size_t)2*65536, w, lane, acc);
    __syncthreads();   // ao reads done before tile overwrite
#pragma unroll
    for (int i = 0; i < 2; ++i)
#pragma unroll
      for (int mt = 0; mt < 2; ++mt)
#pragma unroll
        for (int r = 0; r < 4; ++r)
          tile[((w*2 + i)*16 + xb)*33 + mt*16 + quad*4 + r] = acc[mt][i][r];
  }
  __syncthreads();
  {
    const float bo = LD(opb, o, bf);
    const bf16* tb = (const bf16*)(ws + OF_TB) + ((size_t)n*PP + p0)*CD + o;
#pragma unroll
    for (int xi = 0; xi < 16; ++xi) {
      const int x = half*16 + xi;
      tile[o*33 + x] += bo + bf2f(tb[(size_t)x*CD]);
    }
  }
  __syncthreads();
  ln_reduce512(tile, red, tid);
  {
    const float g = LD(ng, o, bf), bb = LD(nbv, o, bf);
#pragma unroll
    for (int xi = 0; xi < 16; ++xi) {
      const int x = half*16 + xi;
      const bf16 fv = f2bf((tile[o*33 + x] - red[1024 + x]) * red[1056 + x] * g + bb);
      AsF[x*264 + o] = *(const short*)&fv;
    }
  }
  __syncthreads();   // AsF ready; tile dead

  // ---- lin1: f2a -> AsT region ----
  {
    float4v acc[2][2];
#pragma unroll
    for (int mt = 0; mt < 2; ++mt) { acc[mt][0] = (float4v)0.f; acc[mt][1] = (float4v)0.f; }
    mfma_core512(AsF, PK + (size_t)3*65536, w, lane, acc);
#pragma unroll
    for (int i = 0; i < 2; ++i) {
      const int c = (w*2 + i)*16 + xb;
      const float bias = LD(l1b, c, bf);
#pragma unroll
      for (int mt = 0; mt < 2; ++mt)
#pragma unroll
        for (int r = 0; r < 4; ++r) {
          const bf16 fv = f2bf(fmaxf(acc[mt][i][r] + bias, 0.f));
          AsT[(mt*16 + quad*4 + r)*264 + c] = *(const short*)&fv;
        }
    }
  }
  __syncthreads();

  // ---- lin2 + LN + conditional commit ----
  {
    float4v acc[2][2];
#pragma unroll
    for (int mt = 0; mt < 2; ++mt) { acc[mt][0] = (float4v)0.f; acc[mt][1] = (float4v)0.f; }
    mfma_core512(AsT, PK + (size_t)4*65536, w, lane, acc);
    __syncthreads();   // f2a reads done before tile overwrite
#pragma unroll
    for (int i = 0; i < 2; ++i)
#pragma unroll
      for (int mt = 0; mt < 2; ++mt)
#pragma unroll
        for (int r = 0; r < 4; ++r)
          tile[((w*2 + i)*16 + xb)*33 + mt*16 + quad*4 + r] = acc[mt][i][r];
  }
  __syncthreads();
  {
    const float bb = LD(l2b, o, bf);
#pragma unroll
    for (int xi = 0; xi < 16; ++xi) {
      const int x = half*16 + xi;
      bf16 fv; *(short*)&fv = AsF[x*264 + o];
      tile[o*33 + x] += bb + bf2f(fv);
    }
  }
  __syncthreads();
  ln_reduce512(tile, red, tid);
  if (words[s] != 0) {
    const float g = LD(nfg, o, bf), b2 = LD(nfb, o, bf);
    bf16* fbd = (bf16*)(ws + OF_FEATB) + ((size_t)n*PP + p0)*CD + o;
#pragma unroll
    for (int xi = 0; xi < 16; ++xi) {
      const int x = half*16 + xi;
      fbd[(size_t)x*CD] = f2bf((tile[o*33 + x] - red[1024 + x]) * red[1056 + x] * g + b2);
    }
  }
}

// output [n][c][p] from bf16 feat [n][p][c]
__global__ __launch_bounds__(256) void k_final(const float* __restrict__ ws, void* __restrict__ out) {
  const int bf = get_bf(ws);
  const size_t i = (size_t)blockIdx.x*256 + threadIdx.x;
  const int n = (int)(i >> 18), c = (int)((i >> 10) & 255), p = (int)(i & 1023);
  const bf16* fb = (const bf16*)(ws + OF_FEATB);
  float v = bf2f(fb[((size_t)(n*PP + p))*CD + c]);
  if (bf) ((bf16*)out)[i] = f2bf(v);
  else    ((float*)out)[i] = v;
}

extern "C" void kernel_launch(void* const* d_in, const int* in_sizes, int n_in,
                              void* d_out, int out_size, void* d_ws, size_t ws_size,
                              hipStream_t stream) {
  (void)in_sizes; (void)n_in; (void)out_size; (void)ws_size;
  const void* hn      = d_in[1];
  const void* feature = d_in[2];
  const void* emb     = d_in[3];
  const int*  words   = (const int*)d_in[4];
  const void* qw  = d_in[5];
  const void* qb  = d_in[6];
  const void* mw  = d_in[7];
  const void* mg  = d_in[8];
  const void* mb  = d_in[9];
  const void* ipw = d_in[10];
  const void* ipb = d_in[11];
  const void* opw = d_in[12];
  const void* opb = d_in[13];
  const void* ng  = d_in[14];
  const void* nb  = d_in[15];
  const void* l1w = d_in[16];
  const void* l1b = d_in[17];
  const void* l2w = d_in[18];
  const void* l2b = d_in[19];
  const void* nfg = d_in[20];
  const void* nfb = d_in[21];
  float* ws = (float*)d_ws;

  k_detect<<<1, 64, 0, stream>>>(mg, ws);
  k_init<<<NB*PP, 256, 0, stream>>>(feature, ws);
  k_qh<<<SEQL*NB, 256, 0, stream>>>(emb, qw, qb, ipw, ipb, ws);
  k_wregion<<<(9*CD*HND)/256, 256, 0, stream>>>(mw, ws);
  k_hnw<<<9*NB, 256, 0, stream>>>(hn, ws);
  k_sconv<<<PP, 256, 0, stream>>>(mw, ws);
  k_wpack<<<(9*8*16*64*8)/256, 256, 0, stream>>>(mw, ws);
  k_wpackB<<<(5*65536)/256, 256, 0, stream>>>(ipw, opw, l1w, l2w, ws);

  for (int s = 0; s < SEQL; ++s) {
    k_convkv<<<NB*32, 512, 0, stream>>>(mg, mb, ipb, ws);
    k_attn<<<PP*2, 64, 0, stream>>>(s, ws);
    k_oplin<<<NB*32, 512, 0, stream>>>(opb, ng, nb, l1b, l2b, nfg, nfb, words, s, ws);
  }
  k_final<<<NB*CD*PP/256, 256, 0, stream>>>(ws, (void*)d_out);
}

// Round 9
// 1779.899 us; speedup vs baseline: 1.3310x; 1.0129x over previous
//
#include <hip/hip_runtime.h>
#include <hip/hip_bf16.h>
#include <cstddef>

typedef __hip_bfloat16 bf16;
typedef short short8 __attribute__((ext_vector_type(8)));
typedef float float4v __attribute__((ext_vector_type(4)));
#define DEV static __device__ __forceinline__

constexpr int NB = 16;     // batch
constexpr int SEQL = 20;
constexpr int CD = 256;    // VD
constexpr int PP = 1024;   // 32*32
constexpr int HND = 512;
constexpr int EMBD = 300;
constexpr int CIN = 776;   // 256 + 8 + 512

// ---- workspace layout (float element offsets); bf16 buffers are [n][p][c] ----
constexpr size_t SZB = (size_t)NB * PP * CD / 2;             // floats per bf16 NPC buffer
constexpr size_t OF_FEATB = 0;                               // running feature (bf16)
constexpr size_t OF_TB   = 1*SZB;                            // t (bf16)
constexpr size_t OF_KHB  = 2*SZB;                            // kh (bf16)
constexpr size_t OF_VVB  = 3*SZB;                            // vv (bf16)
constexpr size_t OF_AOB  = 4*SZB;                            // attn out (bf16)
constexpr size_t OF_QH   = 7*SZB;                            // qh [s][n][c] fp32
constexpr size_t OF_HNW  = OF_QH  + (size_t)SEQL*NB*CD;      // hnW [r][n][o] fp32
constexpr size_t OF_SCV  = OF_HNW + (size_t)9*NB*CD;         // sconv [p][o] fp32
constexpr size_t OF_WRG  = OF_SCV + (size_t)PP*CD;           // W_region [r][o][c] fp32
constexpr size_t OF_AW   = OF_WRG + (size_t)9*CD*HND;        // conv W A-frags (589,824 bf16)
constexpr size_t OF_PK   = OF_AW  + (size_t)294912;          // linear W B-frags: 5 x 65,536 bf16
constexpr size_t OF_FLAG = OF_PK  + (size_t)163840;          // dtype flag

DEV float bf2f(bf16 v) { return __bfloat162float(v); }
DEV bf16 f2bf(float v) { return __float2bfloat16(v); }

DEV float LD(const void* p, size_t i, int bf) {
  return bf ? __bfloat162float(((const bf16*)p)[i]) : ((const float*)p)[i];
}
DEV int get_bf(const float* ws) { return ((const int*)ws)[OF_FLAG]; }

__global__ void k_detect(const void* g, float* ws) {
  if (threadIdx.x == 0 && blockIdx.x == 0) {
    unsigned w = *(const unsigned*)g;
    ((int*)ws)[OF_FLAG] = ((w & 0xFFFFu) != 0u) ? 1 : 0;
  }
}

// LN reduction, 512 threads: tile[o][x] stride 33; red[1024+x]=mean, red[1056+x]=rstd
DEV void ln_reduce512(const float* tile, float* red, int tid) {
  const int x = tid & 31, seg = tid >> 5;   // 16 segs of 16 channels
  float s = 0.f, sq = 0.f;
#pragma unroll
  for (int i = 0; i < 16; ++i) {
    float v = tile[(seg*16 + i)*33 + x];
    s += v; sq += v*v;
  }
  red[seg*32 + x] = s;
  red[512 + seg*32 + x] = sq;
  __syncthreads();
  if (tid < 32) {
    float ts = 0.f, tq = 0.f;
#pragma unroll
    for (int g = 0; g < 16; ++g) { ts += red[g*32 + tid]; tq += red[512 + g*32 + tid]; }
    float m = ts * (1.f/CD);
    float var = tq * (1.f/CD) - m*m;
    red[1024 + tid] = m;
    red[1056 + tid] = 1.f / sqrtf(var + 1e-5f);
  }
  __syncthreads();
}

// stage 32 rows x 256 cols bf16 -> LDS As[32][264], 512 threads
DEV void stageA512(const bf16* __restrict__ src, short* __restrict__ As, int tid) {
  const int r = tid >> 4, c0 = (tid & 15)*16;
#pragma unroll
  for (int i = 0; i < 2; ++i) {
    short8 v = *(const short8*)&src[(size_t)r*CD + c0 + i*8];
    *(short8*)&As[r*264 + c0 + i*8] = v;
  }
}

// 512-thr linear core with depth-1 prefetch on global B: wave w owns c-tiles {2w,2w+1}
DEV void mfma_core512(const short* __restrict__ As, const short* __restrict__ PKg,
                      int w, int lane, float4v acc[2][2]) {
  const int xb = lane & 15, quad = lane >> 4;
  const short* base = PKg + lane*8;
  short8 b0c = *(const short8*)&base[(size_t)((w*2+0)*8 + 0)*512];
  short8 b1c = *(const short8*)&base[(size_t)((w*2+1)*8 + 0)*512];
#pragma unroll
  for (int ch = 0; ch < 8; ++ch) {
    short8 b0n, b1n;
    if (ch < 7) {
      b0n = *(const short8*)&base[(size_t)((w*2+0)*8 + ch+1)*512];
      b1n = *(const short8*)&base[(size_t)((w*2+1)*8 + ch+1)*512];
    }
    short8 a0 = *(const short8*)&As[xb*264 + ch*32 + quad*8];
    short8 a1 = *(const short8*)&As[(16+xb)*264 + ch*32 + quad*8];
    acc[0][0] = __builtin_amdgcn_mfma_f32_16x16x32_bf16(a0, b0c, acc[0][0], 0, 0, 0);
    acc[0][1] = __builtin_amdgcn_mfma_f32_16x16x32_bf16(a0, b1c, acc[0][1], 0, 0, 0);
    acc[1][0] = __builtin_amdgcn_mfma_f32_16x16x32_bf16(a1, b0c, acc[1][0], 0, 0, 0);
    acc[1][1] = __builtin_amdgcn_mfma_f32_16x16x32_bf16(a1, b1c, acc[1][1], 0, 0, 0);
    if (ch < 7) { b0c = b0n; b1c = b1n; }
  }
}

// ---------------- prep kernels ----------------

__global__ __launch_bounds__(256) void k_init(const void* __restrict__ f, float* __restrict__ ws) {
  const int bf = get_bf(ws);
  const int b = blockIdx.x;
  const int n = b >> 10, p = b & 1023;
  const int c = threadIdx.x;
  bf16* fb = (bf16*)(ws + OF_FEATB);
  fb[(size_t)b*CD + c] = f2bf(LD(f, ((size_t)n*CD + c)*PP + p, bf));
}

__global__ __launch_bounds__(256) void k_qh(const void* __restrict__ emb, const void* __restrict__ qw,
                                            const void* __restrict__ qb, const void* __restrict__ ipw,
                                            const void* __restrict__ ipb, float* __restrict__ ws) {
  const int bf = get_bf(ws);
  const int b = blockIdx.x, s = b / NB, n = b % NB;
  const int o = threadIdx.x;
  __shared__ float se[EMBD];
  __shared__ float sq[CD];
  for (int i = o; i < EMBD; i += CD) se[i] = LD(emb, ((size_t)n*SEQL + s)*EMBD + i, bf);
  __syncthreads();
  float a = LD(qb, o, bf);
  if (bf) {
    const bf16* wr = (const bf16*)qw + (size_t)o*EMBD;
    for (int c = 0; c < EMBD; ++c) a += se[c]*bf2f(wr[c]);
  } else {
    const float* wr = (const float*)qw + (size_t)o*EMBD;
    for (int c = 0; c < EMBD; ++c) a += se[c]*wr[c];
  }
  sq[o] = fmaxf(a, 0.f);
  __syncthreads();
  float a2 = LD(ipb, o, bf);
  if (bf) {
    const bf16* wq = (const bf16*)ipw + (size_t)o*CD;
    for (int c = 0; c < CD; ++c) a2 += sq[c]*bf2f(wq[c]);
  } else {
    const float* wq = (const float*)ipw + (size_t)o*CD;
    for (int c = 0; c < CD; ++c) a2 += sq[c]*wq[c];
  }
  ws[OF_QH + ((size_t)s*NB + n)*CD + o] = a2;
}

__global__ __launch_bounds__(256) void k_wregion(const void* __restrict__ mw, float* __restrict__ ws) {
  const int bf = get_bf(ws);
  const int gid = blockIdx.x*256 + threadIdx.x;
  const int c = gid & (HND-1);
  const int o = (gid >> 9) & (CD-1);
  const int r = gid >> 17;
  const int ry = r/3, rx = r%3;
  float s = 0.f;
  for (int dy = 0; dy < 3; ++dy) {
    if (ry == 0 && dy == 0) continue;
    if (ry == 2 && dy == 2) continue;
    for (int dx = 0; dx < 3; ++dx) {
      if (rx == 0 && dx == 0) continue;
      if (rx == 2 && dx == 2) continue;
      s += LD(mw, ((size_t)o*CIN + 264 + c)*9 + dy*3 + dx, bf);
    }
  }
  ws[OF_WRG + gid] = s;
}

__global__ __launch_bounds__(256) void k_hnw(const void* __restrict__ hn, float* __restrict__ ws) {
  const int bf = get_bf(ws);
  const int b = blockIdx.x, r = b / NB, n = b % NB;
  const int o = threadIdx.x;
  __shared__ float sh[HND];
  for (int i = o; i < HND; i += CD) sh[i] = LD(hn, (size_t)n*HND + i, bf);
  __syncthreads();
  const float* wr = ws + OF_WRG + ((size_t)r*CD + o)*HND;
  float a = 0.f;
  for (int c = 0; c < HND; ++c) a += sh[c]*wr[c];
  ws[OF_HNW + ((size_t)r*NB + n)*CD + o] = a;
}

DEV float spat(int c, int yy, int xx) {
  switch (c) {
    case 0: return xx*(1.f/16) - 1.f;
    case 1: return yy*(1.f/16) - 1.f;
    case 2: return (xx+1)*(1.f/16) - 1.f;
    case 3: return (yy+1)*(1.f/16) - 1.f;
    case 4: return (xx+0.5f)*(1.f/16) - 1.f;
    case 5: return (yy+0.5f)*(1.f/16) - 1.f;
    default: return 1.f/32;
  }
}

__global__ __launch_bounds__(256) void k_sconv(const void* __restrict__ mw, float* __restrict__ ws) {
  const int bf = get_bf(ws);
  const int p = blockIdx.x, o = threadIdx.x;
  const int y = p >> 5, x = p & 31;
  float a = 0.f;
  for (int c = 0; c < 8; ++c)
    for (int dy = 0; dy < 3; ++dy) {
      int yy = y + dy - 1; if ((unsigned)yy >= 32u) continue;
      for (int dx = 0; dx < 3; ++dx) {
        int xx = x + dx - 1; if ((unsigned)xx >= 32u) continue;
        a += LD(mw, ((size_t)o*CIN + 256 + c)*9 + dy*3 + dx, bf) * spat(c, yy, xx);
      }
    }
  ws[OF_SCV + (size_t)p*CD + o] = a;
}

// conv feat weights -> MFMA A-frag order: AW[it=tap*8+ch][mt][lane][8]
__global__ __launch_bounds__(256) void k_wpack(const void* __restrict__ mw, float* __restrict__ ws) {
  const int bf = get_bf(ws);
  const int idx = blockIdx.x*256 + threadIdx.x;
  const int j = idx & 7;
  const int lane = (idx >> 3) & 63;
  const int mt = (idx >> 9) & 15;
  const int ch = (idx >> 13) & 7;
  const int tap = idx >> 16;
  const int o = mt*16 + (lane & 15);
  const int c = ch*32 + (lane >> 4)*8 + j;
  bf16* aw = (bf16*)(ws + OF_AW);
  aw[idx] = f2bf(LD(mw, ((size_t)o*CIN + c)*9 + tap, bf));
}

// linear weights -> MFMA B-frag order: PK[g][nt][ch][lane][8]; g: 0=Wk 1=Wv 2=Wo 3=W1 4=W2
__global__ __launch_bounds__(256) void k_wpackB(const void* __restrict__ ipw, const void* __restrict__ opw,
                                                const void* __restrict__ l1w, const void* __restrict__ l2w,
                                                float* __restrict__ ws) {
  const int bf = get_bf(ws);
  const int idx = blockIdx.x*256 + threadIdx.x;
  const int j = idx & 7;
  const int lane = (idx >> 3) & 63;
  const int ch = (idx >> 9) & 7;
  const int nt = (idx >> 12) & 15;
  const int g = idx >> 16;
  const int o = nt*16 + (lane & 15);
  const int k = ch*32 + (lane >> 4)*8 + j;
  float v;
  switch (g) {
    case 0: v = LD(ipw, ((size_t)(256 + o))*CD + k, bf); break;
    case 1: v = LD(ipw, ((size_t)(512 + o))*CD + k, bf); break;
    case 2: v = LD(opw, (size_t)o*CD + k, bf);           break;
    case 3: v = LD(l1w, (size_t)o*CD + k, bf);           break;
    default: v = LD(l2w, (size_t)o*CD + k, bf);          break;
  }
  ((bf16*)(ws + OF_PK))[idx] = f2bf(v);
}

// ---------------- per-step kernels ----------------

// FUSED conv+LN+KV: 512 blocks x 512 thr, block=(n,y).
// Conv K-loop: depth-3 explicit pipeline, per-wave K-stagger (koff = 8w).
__global__ __launch_bounds__(512, 4) void k_convkv(const void* __restrict__ mg, const void* __restrict__ mbv,
                                                   const void* __restrict__ ipb, float* __restrict__ ws) {
  __shared__ float smem[13760];
  short* Xs = (short*)smem;
  float* tile = smem;
  float* red  = smem + 8448;
  short* AsT  = (short*)(smem + 9536);
  const int bfv = get_bf(ws);
  const int b = blockIdx.x, n = b >> 5, y = b & 31;
  const int tid = threadIdx.x;
  const int w = tid >> 6, lane = tid & 63;      // 8 waves
  const int xb = lane & 15, quad = lane >> 4;
  const bf16* fb = (const bf16*)(ws + OF_FEATB);

  // ---- stage input rows y-1..y+1 zero-padded, transposed: Xs[r][1+x][c] ----
  const short8 zero8 = {0,0,0,0,0,0,0,0};
  if (tid < 192) {
    const int r = tid >> 6, xp = ((tid >> 5) & 1) * 33, c0 = (tid & 31)*8;
    *(short8*)&Xs[(r*34 + xp)*264 + c0] = zero8;
  }
#pragma unroll
  for (int u = 0; u < 6; ++u) {
    const int lin = u*512 + tid;
    const int cgrp = lin & 31, xl = (lin >> 5) & 31, r = lin >> 10;
    const int row = y + r - 1;
    short8 v = zero8;
    if ((unsigned)row < 32u)
      v = *(const short8*)&fb[((size_t)(n*PP + row*32 + xl))*CD + cgrp*8];
    *(short8*)&Xs[(r*34 + 1 + xl)*264 + cgrp*8] = v;
  }
  __syncthreads();

  // ---- conv MFMA K-loop: wave w owns o-tiles {2w, 2w+1}; iterations it=(8w+gi)%72 ----
  float4v a00 = (float4v)0.f, a01 = (float4v)0.f, a10 = (float4v)0.f, a11 = (float4v)0.f;
  const bf16* AW = (const bf16*)(ws + OF_AW);
  const int bvec = xb*264 + quad*8;   // vector part of B address

  short8 A0[3], A1[3], B0[3], B1[3];
#define PF(GI, S) do {                                                        \
    const int g_ = (GI) >> 3, ch_ = (GI) & 7;                                 \
    int tap_ = w + g_; if (tap_ >= 9) tap_ -= 9;                              \
    const int dy_ = (tap_ >= 6) ? 2 : ((tap_ >= 3) ? 1 : 0);                  \
    const int dx_ = tap_ - 3*dy_;                                             \
    const bf16* ap_ = AW + (((size_t)(tap_*8 + ch_)*16 + w*2)*64 + lane)*8;   \
    A0[S] = *(const short8*)&ap_[0];                                          \
    A1[S] = *(const short8*)&ap_[512];                                        \
    const short* bp_ = &Xs[(dy_*34 + dx_)*264 + ch_*32 + bvec];               \
    B0[S] = *(const short8*)&bp_[0];                                          \
    B1[S] = *(const short8*)&bp_[16*264];                                     \
  } while (0)

  PF(0, 0); PF(1, 1); PF(2, 2);
#pragma unroll
  for (int gi = 0; gi < 72; ++gi) {
    const int s = gi % 3;
    a00 = __builtin_amdgcn_mfma_f32_16x16x32_bf16(A0[s], B0[s], a00, 0, 0, 0);
    a01 = __builtin_amdgcn_mfma_f32_16x16x32_bf16(A0[s], B1[s], a01, 0, 0, 0);
    a10 = __builtin_amdgcn_mfma_f32_16x16x32_bf16(A1[s], B0[s], a10, 0, 0, 0);
    a11 = __builtin_amdgcn_mfma_f32_16x16x32_bf16(A1[s], B1[s], a11, 0, 0, 0);
    if (gi < 69) PF(gi + 3, s);
  }
#undef PF
  __syncthreads();   // Xs dead

  // ---- tile[o][x] <- frags ----
#pragma unroll
  for (int r = 0; r < 4; ++r) {
    tile[((w*2 + 0)*16 + quad*4 + r)*33 +  0 + xb] = a00[r];
    tile[((w*2 + 0)*16 + quad*4 + r)*33 + 16 + xb] = a01[r];
    tile[((w*2 + 1)*16 + quad*4 + r)*33 +  0 + xb] = a10[r];
    tile[((w*2 + 1)*16 + quad*4 + r)*33 + 16 + xb] = a11[r];
  }
  __syncthreads();

  // ---- + static terms, relu (512 thr: o = tid&255, half = tid>>8) ----
  const int o = tid & 255, half = tid >> 8;
  {
    const int ry = (y == 0) ? 0 : ((y == 31) ? 2 : 1);
    const float* hnw = ws + OF_HNW;
    const float bl = hnw[((size_t)(ry*3+0)*NB + n)*CD + o];
    const float bm = hnw[((size_t)(ry*3+1)*NB + n)*CD + o];
    const float br = hnw[((size_t)(ry*3+2)*NB + n)*CD + o];
    const float* sc = ws + OF_SCV + (size_t)(y*32)*CD + o;
#pragma unroll
    for (int xi = 0; xi < 16; ++xi) {
      const int x = half*16 + xi;
      float v = tile[o*33 + x] + sc[(size_t)x*CD] + (x == 0 ? bl : (x == 31 ? br : bm));
      tile[o*33 + x] = fmaxf(v, 0.f);
    }
  }
  __syncthreads();
  ln_reduce512(tile, red, tid);
  {
    const float g = LD(mg, o, bfv), bb = LD(mbv, o, bfv);
    bf16* tp = (bf16*)(ws + OF_TB) + ((size_t)n*PP + (size_t)y*32)*CD + o;
#pragma unroll
    for (int xi = 0; xi < 16; ++xi) {
      const int x = half*16 + xi;
      const bf16 tv = f2bf((tile[o*33 + x] - red[1024 + x]) * red[1056 + x] * g + bb);
      tp[(size_t)x*CD] = tv;                  // global (outproj residual)
      AsT[x*264 + o] = *(const short*)&tv;    // LDS A-tile for K/V
    }
  }
  __syncthreads();

  // ---- K and V projections from AsT: wave w owns c-tiles {2w, 2w+1} ----
  const short* PK = (const short*)(ws + OF_PK);
  const int p0 = y << 5;
#pragma unroll 1
  for (int G = 0; G < 2; ++G) {
    float4v ac2[2][2];
#pragma unroll
    for (int mt = 0; mt < 2; ++mt) { ac2[mt][0] = (float4v)0.f; ac2[mt][1] = (float4v)0.f; }
    mfma_core512(AsT, PK + (size_t)G*65536, w, lane, ac2);
    bf16* dst = (bf16*)(ws + (G ? OF_VVB : OF_KHB)) + ((size_t)n*PP + p0)*CD;
#pragma unroll
    for (int i = 0; i < 2; ++i) {
      const int c = (w*2 + i)*16 + xb;
      const float bias = LD(ipb, (size_t)(G+1)*256 + c, bfv);
#pragma unroll
      for (int mt = 0; mt < 2; ++mt)
#pragma unroll
        for (int r = 0; r < 4; ++r)
          dst[(size_t)(mt*16 + quad*4 + r)*CD + c] = f2bf(ac2[mt][i][r] + bias);
    }
  }
}

// cross-batch attention: one wave per (p, h); bf16 K/V, fp32 math
__global__ __launch_bounds__(64) void k_attn(int s, float* __restrict__ ws) {
  __shared__ float SQ[16*132], SK[16*132], SV[16*132], SA[16*20];
  const int p = blockIdx.x >> 1, h = blockIdx.x & 1;
  const int lane = threadIdx.x;
  const bf16* khb = (const bf16*)(ws + OF_KHB);
  const bf16* vvb = (const bf16*)(ws + OF_VVB);
  for (int i = lane; i < 16*128; i += 64) {
    const int l = i >> 7, d = i & 127;
    SQ[l*132 + d] = ws[OF_QH + ((size_t)(s*NB + l))*CD + h*128 + d];
    SK[l*132 + d] = bf2f(khb[((size_t)l*PP + p)*CD + h*128 + d]);
    SV[l*132 + d] = bf2f(vvb[((size_t)l*PP + p)*CD + h*128 + d]);
  }
  __syncthreads();
  const int l = lane >> 2, mg = lane & 3;
  float sc[4];
#pragma unroll
  for (int j = 0; j < 4; ++j) {
    const int m = mg*4 + j;
    float a = 0.f;
    for (int d4 = 0; d4 < 128; d4 += 4) {
      float4 q = *(const float4*)&SQ[l*132 + d4];
      float4 k = *(const float4*)&SK[m*132 + d4];
      a += q.x*k.x + q.y*k.y + q.z*k.z + q.w*k.w;
    }
    sc[j] = a * 0.08838834764831845f;
  }
  float mx = fmaxf(fmaxf(sc[0], sc[1]), fmaxf(sc[2], sc[3]));
  mx = fmaxf(mx, __shfl_xor(mx, 1, 64));
  mx = fmaxf(mx, __shfl_xor(mx, 2, 64));
  float sum = 0.f;
#pragma unroll
  for (int j = 0; j < 4; ++j) { sc[j] = __expf(sc[j] - mx); sum += sc[j]; }
  sum += __shfl_xor(sum, 1, 64);
  sum += __shfl_xor(sum, 2, 64);
  const float inv = 1.f / sum;
#pragma unroll
  for (int j = 0; j < 4; ++j) SA[l*20 + mg*4 + j] = sc[j]*inv;
  __syncthreads();
  float oa[32];
#pragma unroll
  for (int d = 0; d < 32; ++d) oa[d] = 0.f;
  for (int m = 0; m < 16; ++m) {
    const float a = SA[l*20 + m];
#pragma unroll
    for (int d4 = 0; d4 < 8; ++d4) {
      float4 v = *(const float4*)&SV[m*132 + mg*32 + d4*4];
      oa[d4*4+0] += a*v.x; oa[d4*4+1] += a*v.y; oa[d4*4+2] += a*v.z; oa[d4*4+3] += a*v.w;
    }
  }
  bf16* dst = (bf16*)(ws + OF_AOB) + ((size_t)l*PP + p)*CD + h*128 + mg*32;
#pragma unroll
  for (int d = 0; d < 32; ++d) dst[d] = f2bf(oa[d]);
}

// FUSED outproj+LN+lin1+lin2+LN+commit: 512 blocks x 512 thr.
__global__ __launch_bounds__(512, 4) void k_oplin(const void* __restrict__ opb, const void* __restrict__ ng,
                                                  const void* __restrict__ nbv, const void* __restrict__ l1b,
                                                  const void* __restrict__ l2b, const void* __restrict__ nfg,
                                                  const void* __restrict__ nfb, const int* __restrict__ words,
                                                  int s, float* __restrict__ ws) {
  __shared__ float smem[13760];
  float* tile = smem;
  float* red  = smem + 8448;
  short* AsT  = (short*)smem;              // ao staging, later f2a (aliases tile)
  short* AsF  = (short*)(smem + 9536);     // fea
  const int bf = get_bf(ws);
  const int b = blockIdx.x, n = b >> 5, p0 = (b & 31) << 5;
  const int tid = threadIdx.x, w = tid >> 6, lane = tid & 63;
  const int xb = lane & 15, quad = lane >> 4;
  const int o = tid & 255, half = tid >> 8;
  const short* PK = (const short*)(ws + OF_PK);

  // ---- outproj ----
  stageA512((const bf16*)(ws + OF_AOB) + ((size_t)n*PP + p0)*CD, AsT, tid);
  __syncthreads();
  {
    float4v acc[2][2];
#pragma unroll
    for (int mt = 0; mt < 2; ++mt) { acc[mt][0] = (float4v)0.f; acc[mt][1] = (float4v)0.f; }
    mfma_core512(AsT, PK + (size_t)2*65536, w, lane, acc);
    __syncthreads();   // ao reads done before tile overwrite
#pragma unroll
    for (int i = 0; i < 2; ++i)
#pragma unroll
      for (int mt = 0; mt < 2; ++mt)
#pragma unroll
        for (int r = 0; r < 4; ++r)
          tile[((w*2 + i)*16 + xb)*33 + mt*16 + quad*4 + r] = acc[mt][i][r];
  }
  __syncthreads();
  {
    const float bo = LD(opb, o, bf);
    const bf16* tb = (const bf16*)(ws + OF_TB) + ((size_t)n*PP + p0)*CD + o;
#pragma unroll
    for (int xi = 0; xi < 16; ++xi) {
      const int x = half*16 + xi;
      tile[o*33 + x] += bo + bf2f(tb[(size_t)x*CD]);
    }
  }
  __syncthreads();
  ln_reduce512(tile, red, tid);
  {
    const float g = LD(ng, o, bf), bb = LD(nbv, o, bf);
#pragma unroll
    for (int xi = 0; xi < 16; ++xi) {
      const int x = half*16 + xi;
      const bf16 fv = f2bf((tile[o*33 + x] - red[1024 + x]) * red[1056 + x] * g + bb);
      AsF[x*264 + o] = *(const short*)&fv;
    }
  }
  __syncthreads();   // AsF ready; tile dead

  // ---- lin1: f2a -> AsT region ----
  {
    float4v acc[2][2];
#pragma unroll
    for (int mt = 0; mt < 2; ++mt) { acc[mt][0] = (float4v)0.f; acc[mt][1] = (float4v)0.f; }
    mfma_core512(AsF, PK + (size_t)3*65536, w, lane, acc);
#pragma unroll
    for (int i = 0; i < 2; ++i) {
      const int c = (w*2 + i)*16 + xb;
      const float bias = LD(l1b, c, bf);
#pragma unroll
      for (int mt = 0; mt < 2; ++mt)
#pragma unroll
        for (int r = 0; r < 4; ++r) {
          const bf16 fv = f2bf(fmaxf(acc[mt][i][r] + bias, 0.f));
          AsT[(mt*16 + quad*4 + r)*264 + c] = *(const short*)&fv;
        }
    }
  }
  __syncthreads();

  // ---- lin2 + LN + conditional commit ----
  {
    float4v acc[2][2];
#pragma unroll
    for (int mt = 0; mt < 2; ++mt) { acc[mt][0] = (float4v)0.f; acc[mt][1] = (float4v)0.f; }
    mfma_core512(AsT, PK + (size_t)4*65536, w, lane, acc);
    __syncthreads();   // f2a reads done before tile overwrite
#pragma unroll
    for (int i = 0; i < 2; ++i)
#pragma unroll
      for (int mt = 0; mt < 2; ++mt)
#pragma unroll
        for (int r = 0; r < 4; ++r)
          tile[((w*2 + i)*16 + xb)*33 + mt*16 + quad*4 + r] = acc[mt][i][r];
  }
  __syncthreads();
  {
    const float bb = LD(l2b, o, bf);
#pragma unroll
    for (int xi = 0; xi < 16; ++xi) {
      const int x = half*16 + xi;
      bf16 fv; *(short*)&fv = AsF[x*264 + o];
      tile[o*33 + x] += bb + bf2f(fv);
    }
  }
  __syncthreads();
  ln_reduce512(tile, red, tid);
  if (words[s] != 0) {
    const float g = LD(nfg, o, bf), b2 = LD(nfb, o, bf);
    bf16* fbd = (bf16*)(ws + OF_FEATB) + ((size_t)n*PP + p0)*CD + o;
#pragma unroll
    for (int xi = 0; xi < 16; ++xi) {
      const int x = half*16 + xi;
      fbd[(size_t)x*CD] = f2bf((tile[o*33 + x] - red[1024 + x]) * red[1056 + x] * g + b2);
    }
  }
}

// output [n][c][p] from bf16 feat [n][p][c]
__global__ __launch_bounds__(256) void k_final(const float* __restrict__ ws, void* __restrict__ out) {
  const int bf = get_bf(ws);
  const size_t i = (size_t)blockIdx.x*256 + threadIdx.x;
  const int n = (int)(i >> 18), c = (int)((i >> 10) & 255), p = (int)(i & 1023);
  const bf16* fb = (const bf16*)(ws + OF_FEATB);
  float v = bf2f(fb[((size_t)(n*PP + p))*CD + c]);
  if (bf) ((bf16*)out)[i] = f2bf(v);
  else    ((float*)out)[i] = v;
}

extern "C" void kernel_launch(void* const* d_in, const int* in_sizes, int n_in,
                              void* d_out, int out_size, void* d_ws, size_t ws_size,
                              hipStream_t stream) {
  (void)in_sizes; (void)n_in; (void)out_size; (void)ws_size;
  const void* hn      = d_in[1];
  const void* feature = d_in[2];
  const void* emb     = d_in[3];
  const int*  words   = (const int*)d_in[4];
  const void* qw  = d_in[5];
  const void* qb  = d_in[6];
  const void* mw  = d_in[7];
  const void* mg  = d_in[8];
  const void* mb  = d_in[9];
  const void* ipw = d_in[10];
  const void* ipb = d_in[11];
  const void* opw = d_in[12];
  const void* opb = d_in[13];
  const void* ng  = d_in[14];
  const void* nb  = d_in[15];
  const void* l1w = d_in[16];
  const void* l1b = d_in[17];
  const void* l2w = d_in[18];
  const void* l2b = d_in[19];
  const void* nfg = d_in[20];
  const void* nfb = d_in[21];
  float* ws = (float*)d_ws;

  k_detect<<<1, 64, 0, stream>>>(mg, ws);
  k_init<<<NB*PP, 256, 0, stream>>>(feature, ws);
  k_qh<<<SEQL*NB, 256, 0, stream>>>(emb, qw, qb, ipw, ipb, ws);
  k_wregion<<<(9*CD*HND)/256, 256, 0, stream>>>(mw, ws);
  k_hnw<<<9*NB, 256, 0, stream>>>(hn, ws);
  k_sconv<<<PP, 256, 0, stream>>>(mw, ws);
  k_wpack<<<(9*8*16*64*8)/256, 256, 0, stream>>>(mw, ws);
  k_wpackB<<<(5*65536)/256, 256, 0, stream>>>(ipw, opw, l1w, l2w, ws);

  for (int s = 0; s < SEQL; ++s) {
    k_convkv<<<NB*32, 512, 0, stream>>>(mg, mb, ipb, ws);
    k_attn<<<PP*2, 64, 0, stream>>>(s, ws);
    k_oplin<<<NB*32, 512, 0, stream>>>(opb, ng, nb, l1b, l2b, nfg, nfb, words, s, ws);
  }
  k_final<<<NB*CD*PP/256, 256, 0, stream>>>(ws, (void*)d_out);
}